// Round 3
// baseline (257.871 us; speedup 1.0000x reference)
//
#include <hip/hip_runtime.h>
#include <hip/hip_cooperative_groups.h>

namespace cg = cooperative_groups;

// AttentionMixerRec: B=256 S=200 D=256 V=100000 L=5 H=4
// Algebra: scores[b,h,l,s] = (q_pre[b,l,:] @ T[l,h]) . emb[b,s,:] / 16
//   with T[l,h] = lin[l]^T @ (WQ[h]^T @ WK[h]);  q_pre = suffix sums of emb rows.
// v3: (a) attn phase A was TA-throughput-bound (64 gathered rows per wave
//     instr = 64 cache lines); now rows staged coalesced into LDS, compute
//     reads LDS + wave-uniform Qt. (b) pre-chain (U,T,qpre,Qt) fused into one
//     cooperative kernel with grid syncs.

#define DD 256
#define SS 200
#define BB 256
#define LL 5
#define HH 4
#define NC 20  // H*L

// ---- device GEMM tile helpers (64x64 C tile, K=256, 256 threads) ----
// atb: C[i,j] = sum_k A[k,i]*B[k,j]
__device__ __forceinline__ void gemm_atb_tile(const float* __restrict__ Ab,
                                              const float* __restrict__ Bb,
                                              float* __restrict__ Cb,
                                              int tile, float* lds) {
    float (*As)[68] = (float(*)[68])lds;
    float (*Bs)[68] = (float(*)[68])(lds + 32 * 68);
    int i0 = (tile >> 2) * 64, j0 = (tile & 3) * 64;
    int t = threadIdx.x;
    int tx = t & 15, ty = t >> 4;
    float acc[4][4] = {};
    for (int k0 = 0; k0 < DD; k0 += 32) {
        #pragma unroll
        for (int r = 0; r < 8; ++r) {
            int e = r * 256 + t;
            int kk = e >> 6, ii = e & 63;
            As[kk][ii] = Ab[(size_t)(k0 + kk) * DD + i0 + ii];
            Bs[kk][ii] = Bb[(size_t)(k0 + kk) * DD + j0 + ii];
        }
        __syncthreads();
        #pragma unroll
        for (int kk = 0; kk < 32; ++kk) {
            float4 av = *(const float4*)&As[kk][tx * 4];
            float4 bv = *(const float4*)&Bs[kk][ty * 4];
            float a[4] = {av.x, av.y, av.z, av.w};
            float b[4] = {bv.x, bv.y, bv.z, bv.w};
            #pragma unroll
            for (int p = 0; p < 4; ++p)
                #pragma unroll
                for (int q = 0; q < 4; ++q)
                    acc[p][q] += a[p] * b[q];
        }
        __syncthreads();
    }
    #pragma unroll
    for (int p = 0; p < 4; ++p) {
        float4 v = {acc[p][0], acc[p][1], acc[p][2], acc[p][3]};
        *(float4*)&Cb[(size_t)(i0 + tx * 4 + p) * DD + j0 + ty * 4] = v;
    }
}

// ab with strided A/C rows: C[i,j] = sum_k A[i,k]*B[k,j]; A row-stride sA, C row-stride sC
__device__ __forceinline__ void gemm_ab_tile(const float* __restrict__ Ab,
                                             const float* __restrict__ Bb,
                                             float* __restrict__ Cb,
                                             int sA, int sC, int tile, float* lds) {
    float (*As)[68] = (float(*)[68])lds;
    float (*Bs)[68] = (float(*)[68])(lds + 32 * 68);
    int i0 = (tile >> 2) * 64, j0 = (tile & 3) * 64;
    int t = threadIdx.x;
    int tx = t & 15, ty = t >> 4;
    float acc[4][4] = {};
    for (int k0 = 0; k0 < DD; k0 += 32) {
        #pragma unroll
        for (int r = 0; r < 8; ++r) {
            int e = r * 256 + t;
            int i = e >> 5, k = e & 31;
            As[k][i] = Ab[(size_t)(i0 + i) * sA + k0 + k];
            int kk = e >> 6, jj = e & 63;
            Bs[kk][jj] = Bb[(size_t)(k0 + kk) * DD + j0 + jj];
        }
        __syncthreads();
        #pragma unroll
        for (int kk = 0; kk < 32; ++kk) {
            float4 av = *(const float4*)&As[kk][tx * 4];
            float4 bv = *(const float4*)&Bs[kk][ty * 4];
            float a[4] = {av.x, av.y, av.z, av.w};
            float b[4] = {bv.x, bv.y, bv.z, bv.w};
            #pragma unroll
            for (int p = 0; p < 4; ++p)
                #pragma unroll
                for (int q = 0; q < 4; ++q)
                    acc[p][q] += a[p] * b[q];
        }
        __syncthreads();
    }
    #pragma unroll
    for (int p = 0; p < 4; ++p) {
        float4 v = {acc[p][0], acc[p][1], acc[p][2], acc[p][3]};
        *(float4*)&Cb[(size_t)(i0 + tx * 4 + p) * sC + j0 + ty * 4] = v;
    }
}

// ---- fused pre-chain (cooperative, 320 blocks x 256 threads) ----
// P1: U[h]=WQ[h]^T WK[h] (blocks 0..63) || qpre (blocks 64..319)
// P2: T[l,h]=lin[l]^T U[h] (320 blocks)
// P3: Qt[b,h,l,:]=qpre[b,l,:] @ T[l,h] (320 blocks)
__global__ __launch_bounds__(256) void k_prep(const float* __restrict__ wq,
                                              const float* __restrict__ wk,
                                              const float* __restrict__ lin,
                                              const int* __restrict__ seq,
                                              const int* __restrict__ slen,
                                              const float* __restrict__ emb,
                                              float* __restrict__ U,
                                              float* __restrict__ T,
                                              float* __restrict__ qpre,
                                              float* __restrict__ Qt) {
    cg::grid_group grid = cg::this_grid();
    __shared__ float lds[2 * 32 * 68];
    int blk = blockIdx.x;
    int t = threadIdx.x;

    // ---- phase 1 ----
    if (blk < 64) {
        int h = blk >> 4;
        gemm_atb_tile(wq + (size_t)h * (DD * DD), wk + (size_t)h * (DD * DD),
                      U + (size_t)h * (DD * DD), blk & 15, lds);
    } else {
        int b = blk - 64;
        int len = slen[b];
        float acc = 0.f;
        int prev = len;
        #pragma unroll
        for (int l = 0; l < LL; ++l) {
            int lo = max(len - 1 - l, 0);
            while (prev > lo) {
                --prev;
                acc += emb[(size_t)seq[b * SS + prev] * DD + t];
            }
            qpre[(size_t)(b * LL + l) * DD + t] = acc;
        }
    }
    __threadfence();
    grid.sync();

    // ---- phase 2: T (z = blk>>4 in 0..19) ----
    {
        int z = blk >> 4;
        int l = z >> 2, h = z & 3;
        gemm_atb_tile(lin + (size_t)l * (DD * DD), U + (size_t)h * (DD * DD),
                      T + (size_t)z * (DD * DD), blk & 15, lds);
    }
    __threadfence();
    grid.sync();

    // ---- phase 3: Qt ----
    {
        int z = blk >> 4;
        int l = z >> 2, h = z & 3;
        gemm_ab_tile(qpre + l * DD, T + (size_t)z * (DD * DD),
                     Qt + (h * LL + l) * DD, LL * DD, HH * LL * DD, blk & 15, lds);
    }
}

// ---- fused attention: scores -> softmax -> p4 pooling -> weighted emb sum ----
// 1024 threads. Phase A: 4 tiles of 64 s-rows staged coalesced into LDS
// (one float4 instr per row per wave); compute thread = (s=t&63, dq, mg) with
// (dq,mg) wave-uniform -> Qt on scalar path; 4-way d-partials combined in LDS.
__global__ __launch_bounds__(1024) void k_attn_out(const int* __restrict__ seq,
                                                   const float* __restrict__ emb,
                                                   const float* __restrict__ Qt,
                                                   float* __restrict__ out) {
    int b = blockIdx.x, t = threadIdx.x;
    int lane = t & 63, wave = t >> 6;

    __shared__ float er[64][260];     // 66.5 KB, pitch 1040 B (16B aligned)
    __shared__ float part[64][105];   // 26.9 KB, [s][mslot*5+dq], pitch spreads banks
    __shared__ float e[NC][256];      // 20.5 KB exp(scores)
    __shared__ float ssum[NC];
    __shared__ float pooled[256];
    __shared__ float par[4][DD];

    int s_lane = t & 63;
    int dq = __builtin_amdgcn_readfirstlane((t >> 6) & 3);   // wave-uniform
    int mg = __builtin_amdgcn_readfirstlane(t >> 8);         // wave-uniform (= h)
    const float* qbase = Qt + (size_t)b * (NC * DD) + (size_t)(mg * 5) * DD + dq * 64;

    for (int tile = 0; tile < 4; ++tile) {
        // stage rows: wave w loads rows 4w..4w+3, one float4 instr per row
        #pragma unroll
        for (int j = 0; j < 4; ++j) {
            int r = wave * 4 + j;
            int s = tile * 64 + r;
            if (s < SS) {
                int row = __builtin_amdgcn_readfirstlane(seq[b * SS + s]);
                float4 v = ((const float4*)(emb + (size_t)row * DD))[lane];
                *(float4*)&er[r][lane * 4] = v;
            }
        }
        __syncthreads();

        // partial scores over d in [dq*64, dq*64+64) for 5 channels mg*5..+4
        float acc[5] = {0.f, 0.f, 0.f, 0.f, 0.f};
        #pragma unroll
        for (int dj = 0; dj < 16; ++dj) {
            float4 ev = *(const float4*)&er[s_lane][dq * 64 + dj * 4];
            #pragma unroll
            for (int mm = 0; mm < 5; ++mm) {
                const float* qm = qbase + mm * DD + dj * 4;   // uniform -> s_load
                acc[mm] = fmaf(ev.x, qm[0], acc[mm]);
                acc[mm] = fmaf(ev.y, qm[1], acc[mm]);
                acc[mm] = fmaf(ev.z, qm[2], acc[mm]);
                acc[mm] = fmaf(ev.w, qm[3], acc[mm]);
            }
        }
        #pragma unroll
        for (int mm = 0; mm < 5; ++mm)
            part[s_lane][(mg * 5 + mm) * 5 + dq] = acc[mm];
        __syncthreads();

        // combine 4 d-partials -> exp(score) ; 1280 (s,m) pairs
        for (int p = t; p < 64 * NC; p += 1024) {
            int s = p & 63, mslot = p >> 6;
            float sum = part[s][mslot * 5 + 0] + part[s][mslot * 5 + 1] +
                        part[s][mslot * 5 + 2] + part[s][mslot * 5 + 3];
            int sg = tile * 64 + s;
            e[mslot][sg] = (sg < SS) ? __expf(sum * 0.0625f) : 0.f;
        }
        __syncthreads();   // also protects er/part for next tile
    }

    // per-channel sums over s
    for (int m = wave; m < NC; m += 16) {
        float v = e[m][lane] + e[m][lane + 64] + e[m][lane + 128] + e[m][lane + 192];
        #pragma unroll
        for (int off = 32; off >= 1; off >>= 1) v += __shfl_xor(v, off);
        if (lane == 0) ssum[m] = __frcp_rn(v);   // store reciprocal
    }
    __syncthreads();

    // pooled[s] = 0.25 * sum_h (sum_l attn^4)^(1/4)
    if (t < 256) {
        float r = 0.f;
        #pragma unroll
        for (int h = 0; h < HH; ++h) {
            float p4 = 0.f;
            #pragma unroll
            for (int l = 0; l < LL; ++l) {
                int m = h * LL + l;
                float a = e[m][t] * ssum[m];
                float a2 = a * a;
                p4 += a2 * a2;
            }
            r += sqrtf(sqrtf(p4));
        }
        pooled[t] = 0.25f * r;
    }
    __syncthreads();

    // phase C: out[b,d] = sum_s pooled[s] * emb[seq[b,s], d]  (coalesced over d)
    int d = t & 255, sq = t >> 8;
    float o = 0.f;
    for (int i = 0; i < 50; ++i) {
        int s2 = sq * 50 + i;
        int rw = __builtin_amdgcn_readfirstlane(seq[b * SS + s2]);
        o = fmaf(pooled[s2], emb[(size_t)rw * DD + d], o);
    }
    par[sq][d] = o;
    __syncthreads();
    if (t < 256) out[(size_t)b * DD + t] = par[0][t] + par[1][t] + par[2][t] + par[3][t];
}

extern "C" void kernel_launch(void* const* d_in, const int* in_sizes, int n_in,
                              void* d_out, int out_size, void* d_ws, size_t ws_size,
                              hipStream_t stream) {
    const int* seq = (const int*)d_in[0];
    const int* slen = (const int*)d_in[1];
    const float* emb = (const float*)d_in[2];
    const float* lin = (const float*)d_in[3];
    const float* wq = (const float*)d_in[4];
    const float* wk = (const float*)d_in[5];
    float* out = (float*)d_out;
    float* ws = (float*)d_ws;

    float* U    = ws;                // H * D*D          = 262144 floats
    float* T    = ws + 262144;       // L*H * D*D        = 1310720
    float* qpre = ws + 1572864;      // B*L*D            = 327680
    float* Qt   = ws + 1900544;      // B*H*L*D          = 1310720

    void* args[] = { (void*)&wq, (void*)&wk, (void*)&lin, (void*)&seq, (void*)&slen,
                     (void*)&emb, (void*)&U, (void*)&T, (void*)&qpre, (void*)&Qt };
    hipLaunchCooperativeKernel((const void*)k_prep, dim3(320), dim3(256), args, 0, stream);

    k_attn_out<<<dim3(BB), dim3(1024), 0, stream>>>(seq, emb, Qt, out);
}

// Round 4
// 133.277 us; speedup vs baseline: 1.9349x; 1.9349x over previous
//
#include <hip/hip_runtime.h>

// AttentionMixerRec: B=256 S=200 D=256 V=100000 L=5 H=4
// scores[b,h,l,s] = (ql[b,l] @ U[h]) . emb[b,s] / 16
//   U[h] = WQ[h]^T WK[h];  ql[b,l] = qpre[b,l] @ lin[l]^T;
//   qpre[b,l] = sum of emb rows s in [max(len-1-l,0), len-1]  (<=5 rows total).
// v4: cooperative grid.sync was 195us of stall -> plain kernel chain.
//     GEMMs were LDS-throughput-bound (0.5 float/FMA re-read) -> SGPR-B GEMM:
//     wave owns 8 cols, B via wave-uniform scalar loads (v_fmac v,s,v),
//     only A staged in LDS (transposed, pad 76, b128-aligned). 0.125 float/FMA.
//     Dropped T (336M MAC) via ql re-association.

#define DD 256
#define SS 200
#define BB 256
#define LL 5
#define HH 4
#define NC 20  // H*L

// ---- SGPR-B GEMM tile: C[i0..i0+63, n0..n0+31] = sum_k A.B, K=256 ----
// A_KMAJOR: A[k*lda + i] else A[i*lda + k]
// B_KMAJOR: B[k*ldb + n] else B[n*ldb + k]
template<bool A_KMAJOR, bool B_KMAJOR>
__device__ __forceinline__ void gemm_sb(const float* __restrict__ A, int lda,
                                        const float* __restrict__ B, int ldb,
                                        float* __restrict__ C, int ldc,
                                        int i0, int n0, float* lds) {
    float (*As)[76] = (float(*)[76])lds;    // [64][76] pad: b128-aligned, 8/bank
    const int t = threadIdx.x;
    const int lane = t & 63;
    const int wv = __builtin_amdgcn_readfirstlane(t >> 6);
    const int c0 = n0 + wv * 8;             // wave-uniform col base -> s_loads
    float acc[8] = {};
    for (int k0 = 0; k0 < DD; k0 += 64) {
        if (A_KMAJOR) {
            int i = t & 63, kg = t >> 6;
            #pragma unroll
            for (int j = 0; j < 16; ++j) {
                int k = kg * 16 + j;
                As[i][k] = A[(size_t)(k0 + k) * lda + i0 + i];   // coalesced rows
            }
        } else {
            int ii = t >> 4, kk = (t & 15) * 4;
            #pragma unroll
            for (int j = 0; j < 4; ++j) {
                int i = ii + j * 16;
                float4 v = *(const float4*)&A[(size_t)(i0 + i) * lda + k0 + kk];
                *(float4*)&As[i][kk] = v;
            }
        }
        __syncthreads();
        for (int k4 = 0; k4 < 64; k4 += 4) {
            float4 av = *(const float4*)&As[lane][k4];
            float a[4] = {av.x, av.y, av.z, av.w};
            #pragma unroll
            for (int kk2 = 0; kk2 < 4; ++kk2) {
                int k = k0 + k4 + kk2;
                #pragma unroll
                for (int q = 0; q < 8; ++q) {
                    float bv = B_KMAJOR ? B[(size_t)k * ldb + c0 + q]
                                        : B[(size_t)(c0 + q) * ldb + k];
                    acc[q] = fmaf(a[kk2], bv, acc[q]);
                }
            }
        }
        __syncthreads();
    }
    #pragma unroll
    for (int q = 0; q < 8; q += 4) {
        float4 v = {acc[q], acc[q + 1], acc[q + 2], acc[q + 3]};
        *(float4*)&C[(size_t)(i0 + lane) * ldc + c0 + q] = v;
    }
}

// ---- k_pre1: blocks 0..127 = U tiles; blocks 128..383 = qpre ----
__global__ __launch_bounds__(256) void k_pre1(const float* __restrict__ wq,
                                              const float* __restrict__ wk,
                                              const int* __restrict__ seq,
                                              const int* __restrict__ slen,
                                              const float* __restrict__ emb,
                                              float* __restrict__ U,
                                              float* __restrict__ qpre) {
    __shared__ float lds[64 * 76];
    int blk = blockIdx.x;
    if (blk < 128) {
        int h = blk >> 5, rem = blk & 31;
        int i0 = (rem & 3) * 64, n0 = (rem >> 2) * 32;
        gemm_sb<true, true>(wq + (size_t)h * 65536, DD,
                            wk + (size_t)h * 65536, DD,
                            U + (size_t)h * 65536, DD, i0, n0, lds);
    } else {
        int b = blk - 128, t = threadIdx.x;
        int len = slen[b];
        float acc = 0.f;
        int prev = len;
        #pragma unroll
        for (int l = 0; l < LL; ++l) {
            int lo = max(len - 1 - l, 0);
            while (prev > lo) {
                --prev;
                acc += emb[(size_t)seq[b * SS + prev] * DD + t];
            }
            qpre[(size_t)b * (LL * DD) + l * DD + t] = acc;
        }
    }
}

// ---- k_ql: ql[b,l,e] = sum_d qpre[b,l,d] * lin[l,e,d]  (160 blocks) ----
__global__ __launch_bounds__(256) void k_ql(const float* __restrict__ qpre,
                                            const float* __restrict__ lin,
                                            float* __restrict__ ql) {
    __shared__ float lds[64 * 76];
    int blk = blockIdx.x;
    int l = blk >> 5, rem = blk & 31;
    int i0 = (rem & 3) * 64, n0 = (rem >> 2) * 32;
    gemm_sb<false, false>(qpre + l * DD, LL * DD,
                          lin + (size_t)l * 65536, DD,
                          ql + l * DD, LL * DD, i0, n0, lds);
}

// ---- k_Qt: Qt[b,(h*5+l),d'] = sum_e ql[b,l,e] * U[h,e,d']  (640 blocks) ----
__global__ __launch_bounds__(256) void k_Qt(const float* __restrict__ ql,
                                            const float* __restrict__ U,
                                            float* __restrict__ Qt) {
    __shared__ float lds[64 * 76];
    int blk = blockIdx.x;
    int l = blk >> 7, rem = blk & 127;
    int h = rem >> 5, r2 = rem & 31;
    int i0 = (r2 & 3) * 64, n0 = (r2 >> 2) * 32;
    gemm_sb<false, true>(ql + l * DD, LL * DD,
                         U + (size_t)h * 65536, DD,
                         Qt + (size_t)(h * LL + l) * DD, NC * DD, i0, n0, lds);
}

// ---- fused attention: scores -> softmax -> p4 pooling -> weighted emb sum ----
__global__ __launch_bounds__(1024) void k_attn_out(const int* __restrict__ seq,
                                                   const float* __restrict__ emb,
                                                   const float* __restrict__ Qt,
                                                   float* __restrict__ out) {
    int b = blockIdx.x, t = threadIdx.x;
    int lane = t & 63, wave = t >> 6;

    __shared__ float er[64][260];     // pitch 1040 B: 16B-aligned, banks even
    __shared__ float part[64][105];
    __shared__ float e[NC][256];
    __shared__ float ssum[NC];
    __shared__ float pooled[256];
    __shared__ float par[4][DD];

    int s_lane = t & 63;
    int dq = __builtin_amdgcn_readfirstlane((t >> 6) & 3);   // wave-uniform
    int mg = __builtin_amdgcn_readfirstlane(t >> 8);         // wave-uniform (= h)
    const float* qbase = Qt + (size_t)b * (NC * DD) + (size_t)(mg * 5) * DD + dq * 64;

    for (int tile = 0; tile < 4; ++tile) {
        #pragma unroll
        for (int j = 0; j < 4; ++j) {
            int r = wave * 4 + j;
            int s = tile * 64 + r;
            if (s < SS) {
                int row = __builtin_amdgcn_readfirstlane(seq[b * SS + s]);
                float4 v = ((const float4*)(emb + (size_t)row * DD))[lane];
                *(float4*)&er[r][lane * 4] = v;
            }
        }
        __syncthreads();

        float acc[5] = {0.f, 0.f, 0.f, 0.f, 0.f};
        #pragma unroll
        for (int dj = 0; dj < 16; ++dj) {
            float4 ev = *(const float4*)&er[s_lane][dq * 64 + dj * 4];
            #pragma unroll
            for (int mm = 0; mm < 5; ++mm) {
                const float* qm = qbase + mm * DD + dj * 4;   // uniform -> s_load
                acc[mm] = fmaf(ev.x, qm[0], acc[mm]);
                acc[mm] = fmaf(ev.y, qm[1], acc[mm]);
                acc[mm] = fmaf(ev.z, qm[2], acc[mm]);
                acc[mm] = fmaf(ev.w, qm[3], acc[mm]);
            }
        }
        #pragma unroll
        for (int mm = 0; mm < 5; ++mm)
            part[s_lane][(mg * 5 + mm) * 5 + dq] = acc[mm];
        __syncthreads();

        for (int p = t; p < 64 * NC; p += 1024) {
            int s = p & 63, mslot = p >> 6;
            float sum = part[s][mslot * 5 + 0] + part[s][mslot * 5 + 1] +
                        part[s][mslot * 5 + 2] + part[s][mslot * 5 + 3];
            int sg = tile * 64 + s;
            e[mslot][sg] = (sg < SS) ? __expf(sum * 0.0625f) : 0.f;
        }
        __syncthreads();
    }

    for (int m = wave; m < NC; m += 16) {
        float v = e[m][lane] + e[m][lane + 64] + e[m][lane + 128] + e[m][lane + 192];
        #pragma unroll
        for (int off = 32; off >= 1; off >>= 1) v += __shfl_xor(v, off);
        if (lane == 0) ssum[m] = __frcp_rn(v);
    }
    __syncthreads();

    if (t < 256) {
        float r = 0.f;
        #pragma unroll
        for (int h = 0; h < HH; ++h) {
            float p4 = 0.f;
            #pragma unroll
            for (int l = 0; l < LL; ++l) {
                int m = h * LL + l;
                float a = e[m][t] * ssum[m];
                float a2 = a * a;
                p4 += a2 * a2;
            }
            r += sqrtf(sqrtf(p4));
        }
        pooled[t] = 0.25f * r;
    }
    __syncthreads();

    int d = t & 255, sq = t >> 8;
    float o = 0.f;
    for (int i = 0; i < 50; ++i) {
        int s2 = sq * 50 + i;
        int rw = __builtin_amdgcn_readfirstlane(seq[b * SS + s2]);
        o = fmaf(pooled[s2], emb[(size_t)rw * DD + d], o);
    }
    par[sq][d] = o;
    __syncthreads();
    if (t < 256) out[(size_t)b * DD + t] = par[0][t] + par[1][t] + par[2][t] + par[3][t];
}

extern "C" void kernel_launch(void* const* d_in, const int* in_sizes, int n_in,
                              void* d_out, int out_size, void* d_ws, size_t ws_size,
                              hipStream_t stream) {
    const int* seq = (const int*)d_in[0];
    const int* slen = (const int*)d_in[1];
    const float* emb = (const float*)d_in[2];
    const float* lin = (const float*)d_in[3];
    const float* wq = (const float*)d_in[4];
    const float* wk = (const float*)d_in[5];
    float* out = (float*)d_out;
    float* ws = (float*)d_ws;

    float* U    = ws;                // H * D*D   = 262144 floats
    float* qpre = ws + 262144;       // B*L*D     = 327680
    float* ql   = ws + 589824;       // B*L*D     = 327680
    float* Qt   = ws + 917504;       // B*H*L*D   = 1310720
    // total 2,228,224 floats = 8.9 MB workspace

    k_pre1<<<dim3(384), dim3(256), 0, stream>>>(wq, wk, seq, slen, emb, U, qpre);
    k_ql<<<dim3(160), dim3(256), 0, stream>>>(qpre, lin, ql);
    k_Qt<<<dim3(640), dim3(256), 0, stream>>>(ql, U, Qt);
    k_attn_out<<<dim3(BB), dim3(1024), 0, stream>>>(seq, emb, Qt, out);
}

// Round 5
// 94.633 us; speedup vs baseline: 2.7250x; 1.4084x over previous
//
#include <hip/hip_runtime.h>

// AttentionMixerRec: B=256 S=200 D=256 V=100000 L=5 H=4
// scores[b,h,l,s] = (ql[b,l] @ U[h]) . emb[b,s] / 16
//   U[h] = WQ[h]^T WK[h];  ql[b,l] = qpre[b,l] @ lin[l]^T;
//   qpre[b,l] = sum of emb rows s in [max(len-1-l,0), len-1].
// v5: v4's SGPR-B GEMMs suspected stalled on s_load latency chains (can't
//     prefetch: 320 SGPRs needed vs ~100 budget) -> revert chain to all-LDS
//     64x64 tiles (v1-style, measured healthy). Layouts l-major so every
//     GEMM has contiguous rows: qpre/ql = [l][b][d], Qt = [h][l][b][d].
//     attn kept as v4 (scalar-Qt) as the controlled variable.

#define DD 256
#define SS 200
#define BB 256
#define LL 5
#define HH 4
#define NC 20  // H*L

// ---- all-LDS GEMM tile: C[i0..+63, j0..+63] += A.B, K=256, 256 threads ----
// A_T=false: A k-major (A[k*256+i]); A_T=true: A i-major (A[i*256+k])
// B_T=false: B k-major (B[k*256+j]); B_T=true: B j-major (B[j*256+k])
template<bool A_T, bool B_T>
__device__ __forceinline__ void gemm64(const float* __restrict__ A,
                                       const float* __restrict__ B,
                                       float* __restrict__ C,
                                       int tile) {
    __shared__ float As[32][68];
    __shared__ float Bs[32][68];
    int i0 = (tile >> 2) * 64, j0 = (tile & 3) * 64;
    int t = threadIdx.x;
    int tx = t & 15, ty = t >> 4;
    float acc[4][4] = {};
    for (int k0 = 0; k0 < DD; k0 += 32) {
        #pragma unroll
        for (int r = 0; r < 8; ++r) {
            int e = r * 256 + t;
            if (A_T) {
                int i = e >> 5, k = e & 31;           // coalesced: 2 rows x 128B
                As[k][i] = A[(size_t)(i0 + i) * DD + k0 + k];
            } else {
                int kk = e >> 6, ii = e & 63;          // coalesced: row segments
                As[kk][ii] = A[(size_t)(k0 + kk) * DD + i0 + ii];
            }
            if (B_T) {
                int j = e >> 5, k = e & 31;
                Bs[k][j] = B[(size_t)(j0 + j) * DD + k0 + k];
            } else {
                int kk = e >> 6, jj = e & 63;
                Bs[kk][jj] = B[(size_t)(k0 + kk) * DD + j0 + jj];
            }
        }
        __syncthreads();
        #pragma unroll
        for (int kk = 0; kk < 32; ++kk) {
            float4 av = *(const float4*)&As[kk][tx * 4];
            float4 bv = *(const float4*)&Bs[kk][ty * 4];
            float a[4] = {av.x, av.y, av.z, av.w};
            float b[4] = {bv.x, bv.y, bv.z, bv.w};
            #pragma unroll
            for (int p = 0; p < 4; ++p)
                #pragma unroll
                for (int q = 0; q < 4; ++q)
                    acc[p][q] += a[p] * b[q];
        }
        __syncthreads();
    }
    #pragma unroll
    for (int p = 0; p < 4; ++p) {
        float4 v = {acc[p][0], acc[p][1], acc[p][2], acc[p][3]};
        *(float4*)&C[(size_t)(i0 + tx * 4 + p) * DD + j0 + ty * 4] = v;
    }
}

// ---- k_pre1: blocks 0..63 = U[h]=WQ^T WK tiles; 64..319 = qpre gather ----
__global__ __launch_bounds__(256) void k_pre1(const float* __restrict__ wq,
                                              const float* __restrict__ wk,
                                              const int* __restrict__ seq,
                                              const int* __restrict__ slen,
                                              const float* __restrict__ emb,
                                              float* __restrict__ U,
                                              float* __restrict__ qpre) {
    int blk = blockIdx.x;
    if (blk < 64) {
        int h = blk >> 4;
        gemm64<false, false>(wq + (size_t)h * 65536, wk + (size_t)h * 65536,
                             U + (size_t)h * 65536, blk & 15);
    } else {
        int b = blk - 64, t = threadIdx.x;
        int len = slen[b];
        float acc = 0.f;
        int prev = len;
        #pragma unroll
        for (int l = 0; l < LL; ++l) {
            int lo = max(len - 1 - l, 0);
            while (prev > lo) {
                --prev;
                acc += emb[(size_t)seq[b * SS + prev] * DD + t];
            }
            qpre[(size_t)(l * BB + b) * DD + t] = acc;   // [l][b][d]
        }
    }
}

// ---- k_ql: ql[l][b][e] = sum_d qpre[l][b][d] * lin[l][e][d]  (80 blocks) ----
__global__ __launch_bounds__(256) void k_ql(const float* __restrict__ qpre,
                                            const float* __restrict__ lin,
                                            float* __restrict__ ql) {
    int blk = blockIdx.x;
    int l = blk >> 4;
    gemm64<true, true>(qpre + (size_t)l * 65536, lin + (size_t)l * 65536,
                       ql + (size_t)l * 65536, blk & 15);
}

// ---- k_Qt: Qt[h][l][b][e'] = sum_e ql[l][b][e] * U[h][e][e']  (320 blocks) ----
__global__ __launch_bounds__(256) void k_Qt(const float* __restrict__ ql,
                                            const float* __restrict__ U,
                                            float* __restrict__ Qt) {
    int blk = blockIdx.x;
    int z = blk >> 4;            // z = h*5 + l
    int h = z / 5, l = z % 5;
    gemm64<true, false>(ql + (size_t)l * 65536, U + (size_t)h * 65536,
                        Qt + (size_t)z * 65536, blk & 15);
}

// ---- fused attention (unchanged v4 structure; Qt layout [m][b][d]) ----
__global__ __launch_bounds__(1024) void k_attn_out(const int* __restrict__ seq,
                                                   const float* __restrict__ emb,
                                                   const float* __restrict__ Qt,
                                                   float* __restrict__ out) {
    int b = blockIdx.x, t = threadIdx.x;
    int lane = t & 63, wave = t >> 6;

    __shared__ float er[64][260];     // pitch 1040B: 16B-aligned, uniform banks
    __shared__ float part[64][105];
    __shared__ float e[NC][256];
    __shared__ float ssum[NC];
    __shared__ float pooled[256];
    __shared__ float par[4][DD];

    int s_lane = t & 63;
    int dq = __builtin_amdgcn_readfirstlane((t >> 6) & 3);   // wave-uniform
    int mg = __builtin_amdgcn_readfirstlane(t >> 8);         // wave-uniform (= h)
    // Qt row for channel m: Qt[(m*256 + b)*256 + d]
    const float* qbase = Qt + ((size_t)(mg * 5) * BB + b) * DD + dq * 64;

    for (int tile = 0; tile < 4; ++tile) {
        #pragma unroll
        for (int j = 0; j < 4; ++j) {
            int r = wave * 4 + j;
            int s = tile * 64 + r;
            if (s < SS) {
                int row = __builtin_amdgcn_readfirstlane(seq[b * SS + s]);
                float4 v = ((const float4*)(emb + (size_t)row * DD))[lane];
                *(float4*)&er[r][lane * 4] = v;
            }
        }
        __syncthreads();

        float acc[5] = {0.f, 0.f, 0.f, 0.f, 0.f};
        #pragma unroll
        for (int dj = 0; dj < 16; ++dj) {
            float4 ev = *(const float4*)&er[s_lane][dq * 64 + dj * 4];
            #pragma unroll
            for (int mm = 0; mm < 5; ++mm) {
                const float* qm = qbase + (size_t)mm * (BB * DD) + dj * 4;  // s_load
                acc[mm] = fmaf(ev.x, qm[0], acc[mm]);
                acc[mm] = fmaf(ev.y, qm[1], acc[mm]);
                acc[mm] = fmaf(ev.z, qm[2], acc[mm]);
                acc[mm] = fmaf(ev.w, qm[3], acc[mm]);
            }
        }
        #pragma unroll
        for (int mm = 0; mm < 5; ++mm)
            part[s_lane][(mg * 5 + mm) * 5 + dq] = acc[mm];
        __syncthreads();

        for (int p = t; p < 64 * NC; p += 1024) {
            int s = p & 63, mslot = p >> 6;
            float sum = part[s][mslot * 5 + 0] + part[s][mslot * 5 + 1] +
                        part[s][mslot * 5 + 2] + part[s][mslot * 5 + 3];
            int sg = tile * 64 + s;
            e[mslot][sg] = (sg < SS) ? __expf(sum * 0.0625f) : 0.f;
        }
        __syncthreads();
    }

    for (int m = wave; m < NC; m += 16) {
        float v = e[m][lane] + e[m][lane + 64] + e[m][lane + 128] + e[m][lane + 192];
        #pragma unroll
        for (int off = 32; off >= 1; off >>= 1) v += __shfl_xor(v, off);
        if (lane == 0) ssum[m] = __frcp_rn(v);
    }
    __syncthreads();

    if (t < 256) {
        float r = 0.f;
        #pragma unroll
        for (int h = 0; h < HH; ++h) {
            float p4 = 0.f;
            #pragma unroll
            for (int l = 0; l < LL; ++l) {
                int m = h * LL + l;
                float a = e[m][t] * ssum[m];
                float a2 = a * a;
                p4 += a2 * a2;
            }
            r += sqrtf(sqrtf(p4));
        }
        pooled[t] = 0.25f * r;
    }
    __syncthreads();

    int d = t & 255, sq = t >> 8;
    float o = 0.f;
    for (int i = 0; i < 50; ++i) {
        int s2 = sq * 50 + i;
        int rw = __builtin_amdgcn_readfirstlane(seq[b * SS + s2]);
        o = fmaf(pooled[s2], emb[(size_t)rw * DD + d], o);
    }
    par[sq][d] = o;
    __syncthreads();
    if (t < 256) out[(size_t)b * DD + t] = par[0][t] + par[1][t] + par[2][t] + par[3][t];
}

extern "C" void kernel_launch(void* const* d_in, const int* in_sizes, int n_in,
                              void* d_out, int out_size, void* d_ws, size_t ws_size,
                              hipStream_t stream) {
    const int* seq = (const int*)d_in[0];
    const int* slen = (const int*)d_in[1];
    const float* emb = (const float*)d_in[2];
    const float* lin = (const float*)d_in[3];
    const float* wq = (const float*)d_in[4];
    const float* wk = (const float*)d_in[5];
    float* out = (float*)d_out;
    float* ws = (float*)d_ws;

    float* U    = ws;                // H * D*D   = 262144 floats
    float* qpre = ws + 262144;       // [l][b][d] = 327680
    float* ql   = ws + 589824;       // [l][b][d] = 327680
    float* Qt   = ws + 917504;       // [h][l][b][d] = 1310720
    // total 2,228,224 floats = 8.9 MB workspace

    k_pre1<<<dim3(320), dim3(256), 0, stream>>>(wq, wk, seq, slen, emb, U, qpre);
    k_ql<<<dim3(80), dim3(256), 0, stream>>>(qpre, lin, ql);
    k_Qt<<<dim3(320), dim3(256), 0, stream>>>(ql, U, Qt);
    k_attn_out<<<dim3(BB), dim3(1024), 0, stream>>>(seq, emb, Qt, out);
}

// Round 6
// 83.559 us; speedup vs baseline: 3.0861x; 1.1325x over previous
//
#include <hip/hip_runtime.h>

// AttentionMixerRec: B=256 S=200 D=256 V=100000 L=5 H=4
// scores[b,h,l,s] = (ql[b,l] @ U[h]) . emb[b,s] / 16
//   U[h] = WQ[h]^T WK[h];  ql[b,l] = qpre[b,l] @ lin[l]^T;
//   qpre[b,l] = sum of emb rows s in [max(len-1-l,0), len-1].
// v6: v5 proved global wave-uniform s_loads in inner loops stall on SMEM
//     latency (SGPR budget blocks pipelining): chain fix gave -38us. The attn
//     kernel had the same anti-pattern (80 s_load_dwordx4/tile/wave for Qt).
//     Now Qt slice (20KB) is staged in LDS once; inner loop reads it as
//     wave-uniform LDS broadcasts (no conflicts). Chain unchanged from v5.

#define DD 256
#define SS 200
#define BB 256
#define LL 5
#define HH 4
#define NC 20  // H*L

// ---- all-LDS GEMM tile: C[i0..+63, j0..+63] += A.B, K=256, 256 threads ----
template<bool A_T, bool B_T>
__device__ __forceinline__ void gemm64(const float* __restrict__ A,
                                       const float* __restrict__ B,
                                       float* __restrict__ C,
                                       int tile) {
    __shared__ float As[32][68];
    __shared__ float Bs[32][68];
    int i0 = (tile >> 2) * 64, j0 = (tile & 3) * 64;
    int t = threadIdx.x;
    int tx = t & 15, ty = t >> 4;
    float acc[4][4] = {};
    for (int k0 = 0; k0 < DD; k0 += 32) {
        #pragma unroll
        for (int r = 0; r < 8; ++r) {
            int e = r * 256 + t;
            if (A_T) {
                int i = e >> 5, k = e & 31;
                As[k][i] = A[(size_t)(i0 + i) * DD + k0 + k];
            } else {
                int kk = e >> 6, ii = e & 63;
                As[kk][ii] = A[(size_t)(k0 + kk) * DD + i0 + ii];
            }
            if (B_T) {
                int j = e >> 5, k = e & 31;
                Bs[k][j] = B[(size_t)(j0 + j) * DD + k0 + k];
            } else {
                int kk = e >> 6, jj = e & 63;
                Bs[kk][jj] = B[(size_t)(k0 + kk) * DD + j0 + jj];
            }
        }
        __syncthreads();
        #pragma unroll
        for (int kk = 0; kk < 32; ++kk) {
            float4 av = *(const float4*)&As[kk][tx * 4];
            float4 bv = *(const float4*)&Bs[kk][ty * 4];
            float a[4] = {av.x, av.y, av.z, av.w};
            float b[4] = {bv.x, bv.y, bv.z, bv.w};
            #pragma unroll
            for (int p = 0; p < 4; ++p)
                #pragma unroll
                for (int q = 0; q < 4; ++q)
                    acc[p][q] += a[p] * b[q];
        }
        __syncthreads();
    }
    #pragma unroll
    for (int p = 0; p < 4; ++p) {
        float4 v = {acc[p][0], acc[p][1], acc[p][2], acc[p][3]};
        *(float4*)&C[(size_t)(i0 + tx * 4 + p) * DD + j0 + ty * 4] = v;
    }
}

// ---- k_pre1: blocks 0..63 = U[h]=WQ^T WK tiles; 64..319 = qpre gather ----
__global__ __launch_bounds__(256) void k_pre1(const float* __restrict__ wq,
                                              const float* __restrict__ wk,
                                              const int* __restrict__ seq,
                                              const int* __restrict__ slen,
                                              const float* __restrict__ emb,
                                              float* __restrict__ U,
                                              float* __restrict__ qpre) {
    int blk = blockIdx.x;
    if (blk < 64) {
        int h = blk >> 4;
        gemm64<false, false>(wq + (size_t)h * 65536, wk + (size_t)h * 65536,
                             U + (size_t)h * 65536, blk & 15);
    } else {
        int b = blk - 64, t = threadIdx.x;
        int len = slen[b];
        float acc = 0.f;
        int prev = len;
        #pragma unroll
        for (int l = 0; l < LL; ++l) {
            int lo = max(len - 1 - l, 0);
            while (prev > lo) {
                --prev;
                acc += emb[(size_t)seq[b * SS + prev] * DD + t];
            }
            qpre[(size_t)(l * BB + b) * DD + t] = acc;   // [l][b][d]
        }
    }
}

// ---- k_ql: ql[l][b][e] = sum_d qpre[l][b][d] * lin[l][e][d]  (80 blocks) ----
__global__ __launch_bounds__(256) void k_ql(const float* __restrict__ qpre,
                                            const float* __restrict__ lin,
                                            float* __restrict__ ql) {
    int blk = blockIdx.x;
    int l = blk >> 4;
    gemm64<true, true>(qpre + (size_t)l * 65536, lin + (size_t)l * 65536,
                       ql + (size_t)l * 65536, blk & 15);
}

// ---- k_Qt: Qt[h][l][b][e'] = sum_e ql[l][b][e] * U[h][e][e']  (320 blocks) ----
__global__ __launch_bounds__(256) void k_Qt(const float* __restrict__ ql,
                                            const float* __restrict__ U,
                                            float* __restrict__ Qt) {
    int blk = blockIdx.x;
    int z = blk >> 4;            // z = h*5 + l
    int h = z / 5, l = z % 5;
    gemm64<true, false>(ql + (size_t)l * 65536, U + (size_t)h * 65536,
                        Qt + (size_t)z * 65536, blk & 15);
}

// ---- fused attention; Qt layout [m][b][d]; Qt slice staged in LDS ----
__global__ __launch_bounds__(1024) void k_attn_out(const int* __restrict__ seq,
                                                   const float* __restrict__ emb,
                                                   const float* __restrict__ Qt,
                                                   float* __restrict__ out) {
    int b = blockIdx.x, t = threadIdx.x;
    int lane = t & 63, wave = t >> 6;

    __shared__ float er[64][260];     // pitch 1040B: b128 bank pattern == contiguous
    __shared__ float qt[NC][256];     // block's Qt slice; broadcast reads only
    __shared__ float part[64][105];
    __shared__ float e[NC][256];
    __shared__ float ssum[NC];
    __shared__ float pooled[256];
    __shared__ float par[4][DD];
    // LDS total ~140 KB -> 1 block/CU (grid is 256 = 1/CU anyway)

    int s_lane = t & 63;
    int dq = __builtin_amdgcn_readfirstlane((t >> 6) & 3);   // wave-uniform
    int mg = __builtin_amdgcn_readfirstlane(t >> 8);         // wave-uniform (= h)

    // stage Qt[.,b,:] -> LDS: row m loaded by wave m (m<16) / wave m-16
    for (int r = wave; r < NC; r += 16) {
        float4 v = *(const float4*)&Qt[((size_t)r * BB + b) * DD + lane * 4];
        *(float4*)&qt[r][lane * 4] = v;
    }

    for (int tile = 0; tile < 4; ++tile) {
        #pragma unroll
        for (int j = 0; j < 4; ++j) {
            int r = wave * 4 + j;
            int s = tile * 64 + r;
            if (s < SS) {
                int row = __builtin_amdgcn_readfirstlane(seq[b * SS + s]);
                float4 v = ((const float4*)(emb + (size_t)row * DD))[lane];
                *(float4*)&er[r][lane * 4] = v;
            }
        }
        __syncthreads();   // covers qt staging (tile 0) + er tile

        float acc[5] = {0.f, 0.f, 0.f, 0.f, 0.f};
        #pragma unroll
        for (int dj = 0; dj < 16; ++dj) {
            float4 ev = *(const float4*)&er[s_lane][dq * 64 + dj * 4];
            #pragma unroll
            for (int mm = 0; mm < 5; ++mm) {
                float4 qv = *(const float4*)&qt[mg * 5 + mm][dq * 64 + dj * 4];  // broadcast
                acc[mm] = fmaf(ev.x, qv.x, acc[mm]);
                acc[mm] = fmaf(ev.y, qv.y, acc[mm]);
                acc[mm] = fmaf(ev.z, qv.z, acc[mm]);
                acc[mm] = fmaf(ev.w, qv.w, acc[mm]);
            }
        }
        #pragma unroll
        for (int mm = 0; mm < 5; ++mm)
            part[s_lane][(mg * 5 + mm) * 5 + dq] = acc[mm];
        __syncthreads();

        for (int p = t; p < 64 * NC; p += 1024) {
            int s = p & 63, mslot = p >> 6;
            float sum = part[s][mslot * 5 + 0] + part[s][mslot * 5 + 1] +
                        part[s][mslot * 5 + 2] + part[s][mslot * 5 + 3];
            int sg = tile * 64 + s;
            e[mslot][sg] = (sg < SS) ? __expf(sum * 0.0625f) : 0.f;
        }
        __syncthreads();
    }

    for (int m = wave; m < NC; m += 16) {
        float v = e[m][lane] + e[m][lane + 64] + e[m][lane + 128] + e[m][lane + 192];
        #pragma unroll
        for (int off = 32; off >= 1; off >>= 1) v += __shfl_xor(v, off);
        if (lane == 0) ssum[m] = __frcp_rn(v);
    }
    __syncthreads();

    if (t < 256) {
        float r = 0.f;
        #pragma unroll
        for (int h = 0; h < HH; ++h) {
            float p4 = 0.f;
            #pragma unroll
            for (int l = 0; l < LL; ++l) {
                int m = h * LL + l;
                float a = e[m][t] * ssum[m];
                float a2 = a * a;
                p4 += a2 * a2;
            }
            r += sqrtf(sqrtf(p4));
        }
        pooled[t] = 0.25f * r;
    }
    __syncthreads();

    int d = t & 255, sq = t >> 8;
    float o = 0.f;
    for (int i = 0; i < 50; ++i) {
        int s2 = sq * 50 + i;
        int rw = __builtin_amdgcn_readfirstlane(seq[b * SS + s2]);
        o = fmaf(pooled[s2], emb[(size_t)rw * DD + d], o);
    }
    par[sq][d] = o;
    __syncthreads();
    if (t < 256) out[(size_t)b * DD + t] = par[0][t] + par[1][t] + par[2][t] + par[3][t];
}

extern "C" void kernel_launch(void* const* d_in, const int* in_sizes, int n_in,
                              void* d_out, int out_size, void* d_ws, size_t ws_size,
                              hipStream_t stream) {
    const int* seq = (const int*)d_in[0];
    const int* slen = (const int*)d_in[1];
    const float* emb = (const float*)d_in[2];
    const float* lin = (const float*)d_in[3];
    const float* wq = (const float*)d_in[4];
    const float* wk = (const float*)d_in[5];
    float* out = (float*)d_out;
    float* ws = (float*)d_ws;

    float* U    = ws;                // H * D*D   = 262144 floats
    float* qpre = ws + 262144;       // [l][b][d] = 327680
    float* ql   = ws + 589824;       // [l][b][d] = 327680
    float* Qt   = ws + 917504;       // [m][b][d] = 1310720
    // total 2,228,224 floats = 8.9 MB workspace

    k_pre1<<<dim3(320), dim3(256), 0, stream>>>(wq, wk, seq, slen, emb, U, qpre);
    k_ql<<<dim3(80), dim3(256), 0, stream>>>(qpre, lin, ql);
    k_Qt<<<dim3(320), dim3(256), 0, stream>>>(ql, U, Qt);
    k_attn_out<<<dim3(BB), dim3(1024), 0, stream>>>(seq, emb, Qt, out);
}

// Round 7
// 75.167 us; speedup vs baseline: 3.4306x; 1.1116x over previous
//
#include <hip/hip_runtime.h>
#include <hip/hip_bf16.h>

// AttentionMixerRec: B=256 S=200 D=256 V=100000 L=5 H=4
// scores[b,h,l,s] = (ql[b,l] @ U[h]) . emb[b,s] / 16
//   U[h] = WQ[h]^T WK[h];  ql[b,l] = qpre[b,l] @ lin[l]^T;
//   qpre[b,l] = sum of emb rows s in [max(len-1-l,0), len-1].
// v7: attn phase A re-tiled: 4s x 5m x 64d per thread, all 256 s staged once
//     as bf16 (1.4 B/MAC LDS vs 4.8), dj-rotation kills dq bank collapse,
//     shfl_xor combines dq partials (no part[] array). smem 156KB with er
//     region reused for e/pooled/par after phase A. Chain: qpre -> (U || ql)
//     -> Qt so U and ql run concurrently. bf16 only on the score path.

#define DD 256
#define SS 200
#define BB 256
#define LL 5
#define HH 4
#define NC 20   // H*L
#define P_ER 264   // er pitch in halves (16B-multiple, bank-spread w/ rotation)
#define P_QT 260   // qt pitch in floats

__device__ __forceinline__ float bflo(unsigned u) {
    union { unsigned i; float f; } c; c.i = u << 16; return c.f;
}
__device__ __forceinline__ float bfhi(unsigned u) {
    union { unsigned i; float f; } c; c.i = u & 0xffff0000u; return c.f;
}

// ---- all-LDS GEMM tile: C[i0..+63, j0..+63] = A.B, K=256, 256 threads ----
template<bool A_T, bool B_T>
__device__ __forceinline__ void gemm64(const float* __restrict__ A,
                                       const float* __restrict__ B,
                                       float* __restrict__ C,
                                       int tile) {
    __shared__ float As[32][68];
    __shared__ float Bs[32][68];
    int i0 = (tile >> 2) * 64, j0 = (tile & 3) * 64;
    int t = threadIdx.x;
    int tx = t & 15, ty = t >> 4;
    float acc[4][4] = {};
    for (int k0 = 0; k0 < DD; k0 += 32) {
        #pragma unroll
        for (int r = 0; r < 8; ++r) {
            int e = r * 256 + t;
            if (A_T) {
                int i = e >> 5, k = e & 31;
                As[k][i] = A[(size_t)(i0 + i) * DD + k0 + k];
            } else {
                int kk = e >> 6, ii = e & 63;
                As[kk][ii] = A[(size_t)(k0 + kk) * DD + i0 + ii];
            }
            if (B_T) {
                int j = e >> 5, k = e & 31;
                Bs[k][j] = B[(size_t)(j0 + j) * DD + k0 + k];
            } else {
                int kk = e >> 6, jj = e & 63;
                Bs[kk][jj] = B[(size_t)(k0 + kk) * DD + j0 + jj];
            }
        }
        __syncthreads();
        #pragma unroll
        for (int kk = 0; kk < 32; ++kk) {
            float4 av = *(const float4*)&As[kk][tx * 4];
            float4 bv = *(const float4*)&Bs[kk][ty * 4];
            float a[4] = {av.x, av.y, av.z, av.w};
            float b[4] = {bv.x, bv.y, bv.z, bv.w};
            #pragma unroll
            for (int p = 0; p < 4; ++p)
                #pragma unroll
                for (int q = 0; q < 4; ++q)
                    acc[p][q] += a[p] * b[q];
        }
        __syncthreads();
    }
    #pragma unroll
    for (int p = 0; p < 4; ++p) {
        float4 v = {acc[p][0], acc[p][1], acc[p][2], acc[p][3]};
        *(float4*)&C[(size_t)(i0 + tx * 4 + p) * DD + j0 + ty * 4] = v;
    }
}

// ---- k_qpre: suffix-sum gather (256 blocks) ----
__global__ __launch_bounds__(256) void k_qpre(const int* __restrict__ seq,
                                              const int* __restrict__ slen,
                                              const float* __restrict__ emb,
                                              float* __restrict__ qpre) {
    int b = blockIdx.x, t = threadIdx.x;
    int len = slen[b];
    float acc = 0.f;
    int prev = len;
    #pragma unroll
    for (int l = 0; l < LL; ++l) {
        int lo = max(len - 1 - l, 0);
        while (prev > lo) {
            --prev;
            acc += emb[(size_t)seq[b * SS + prev] * DD + t];
        }
        qpre[(size_t)(l * BB + b) * DD + t] = acc;   // [l][b][d]
    }
}

// ---- k_wu: blocks 0..63 = U[h] tiles; blocks 64..143 = ql tiles ----
__global__ __launch_bounds__(256) void k_wu(const float* __restrict__ wq,
                                            const float* __restrict__ wk,
                                            const float* __restrict__ qpre,
                                            const float* __restrict__ lin,
                                            float* __restrict__ U,
                                            float* __restrict__ ql) {
    int blk = blockIdx.x;
    if (blk < 64) {
        int h = blk >> 4;
        gemm64<false, false>(wq + (size_t)h * 65536, wk + (size_t)h * 65536,
                             U + (size_t)h * 65536, blk & 15);
    } else {
        int z = blk - 64;            // ql[l][b][e] = sum_d qpre[l][b][d]*lin[l][e][d]
        int l = z >> 4;
        gemm64<true, true>(qpre + (size_t)l * 65536, lin + (size_t)l * 65536,
                           ql + (size_t)l * 65536, z & 15);
    }
}

// ---- k_Qt: Qt[m=h*5+l][b][e'] = sum_e ql[l][b][e] * U[h][e][e']  (320 blk) ----
__global__ __launch_bounds__(256) void k_Qt(const float* __restrict__ ql,
                                            const float* __restrict__ U,
                                            float* __restrict__ Qt) {
    int blk = blockIdx.x;
    int z = blk >> 4;            // z = h*5 + l
    int h = z / 5, l = z % 5;
    gemm64<true, false>(ql + (size_t)l * 65536, U + (size_t)h * 65536,
                        Qt + (size_t)z * 65536, blk & 15);
}

// ---- fused attention v7 ----
// 1024 thr: lane=(sg<<2)|dq, wave=(mg<<2)|sgg. Thread: 4 s-rows
// {sgg*16+sg+64j}, m in [mg*5, mg*5+5), d in [dq*64, dq*64+64).
__global__ __launch_bounds__(1024, 4) void k_attn_out(const int* __restrict__ seq,
                                                      const float* __restrict__ emb,
                                                      const float* __restrict__ Qt,
                                                      float* __restrict__ out) {
    __shared__ float smem[38992];     // 152.3 KB
    __shared__ float ssum[NC];
    float* qt = smem;                                 // [20][P_QT] f32
    unsigned short* er = (unsigned short*)(smem + 5200);  // [256][P_ER] bf16
    float* e      = smem + 5200;                      // overlay after phase A
    float* pooled = smem + 5200 + NC * 256;           // [256]
    float* par    = pooled + 256;                     // [4][256]

    int b = blockIdx.x, t = threadIdx.x;
    int lane = t & 63, wave = t >> 6;
    int sg = lane >> 2, dq = lane & 3;
    int sgg = wave & 3;
    int mg = __builtin_amdgcn_readfirstlane(wave >> 2);

    // stage qt: 20 rows of Qt[.,b,:]
    for (int r = wave; r < NC; r += 16) {
        float4 v = *(const float4*)&Qt[((size_t)r * BB + b) * DD + lane * 4];
        *(float4*)&qt[r * P_QT + lane * 4] = v;
    }
    // stage er: 200 emb rows as bf16 (coalesced 1KB/row/instr)
    for (int r = wave; r < SS; r += 16) {
        int row = __builtin_amdgcn_readfirstlane(seq[b * SS + r]);
        float4 v = *(const float4*)&emb[(size_t)row * DD + lane * 4];
        __hip_bfloat162 p0 = __float22bfloat162_rn(make_float2(v.x, v.y));
        __hip_bfloat162 p1 = __float22bfloat162_rn(make_float2(v.z, v.w));
        union { __hip_bfloat162 h; unsigned u; } c0, c1;
        c0.h = p0; c1.h = p1;
        *(uint2*)&er[r * P_ER + lane * 4] = make_uint2(c0.u, c1.u);
    }
    __syncthreads();

    // phase A: acc[j][mm] = sum_d er[s_j][d] * qt[m][d] over this thread's d-chunk
    float acc[4][5] = {};
    int rbase = sgg * 16 + sg;
    const unsigned short* er0 = er + rbase * P_ER;
    for (int dj = 0; dj < 8; ++dj) {
        int rd = (dj + dq) & 7;            // rotation: de-collides dq banks
        int dcol = dq * 64 + rd * 8;
        float ev[4][8];
        #pragma unroll
        for (int j = 0; j < 4; ++j) {
            uint4 pv = *(const uint4*)&er0[j * 64 * P_ER + dcol];
            ev[j][0] = bflo(pv.x); ev[j][1] = bfhi(pv.x);
            ev[j][2] = bflo(pv.y); ev[j][3] = bfhi(pv.y);
            ev[j][4] = bflo(pv.z); ev[j][5] = bfhi(pv.z);
            ev[j][6] = bflo(pv.w); ev[j][7] = bfhi(pv.w);
        }
        #pragma unroll
        for (int mm = 0; mm < 5; ++mm) {
            const float* qm = &qt[(mg * 5 + mm) * P_QT + dcol];
            float4 q0 = *(const float4*)qm;
            float4 q1 = *(const float4*)(qm + 4);
            #pragma unroll
            for (int j = 0; j < 4; ++j) {
                float a = acc[j][mm];
                a = fmaf(ev[j][0], q0.x, a);
                a = fmaf(ev[j][1], q0.y, a);
                a = fmaf(ev[j][2], q0.z, a);
                a = fmaf(ev[j][3], q0.w, a);
                a = fmaf(ev[j][4], q1.x, a);
                a = fmaf(ev[j][5], q1.y, a);
                a = fmaf(ev[j][6], q1.z, a);
                a = fmaf(ev[j][7], q1.w, a);
                acc[j][mm] = a;
            }
        }
    }
    __syncthreads();   // er dead from here; e/pooled/par overlay safe

    // combine dq partials (xor-reduce in 4-lane groups), exp, write e[m][s]
    #pragma unroll
    for (int j = 0; j < 4; ++j) {
        #pragma unroll
        for (int mm = 0; mm < 5; ++mm) {
            float v = acc[j][mm];
            v += __shfl_xor(v, 1);
            v += __shfl_xor(v, 2);
            if (dq == 0) {
                int s = rbase + 64 * j;
                e[(mg * 5 + mm) * 256 + s] = (s < SS) ? __expf(v * 0.0625f) : 0.f;
            }
        }
    }
    __syncthreads();

    // per-channel softmax denominators (store reciprocal)
    for (int m = wave; m < NC; m += 16) {
        float v = e[m * 256 + lane] + e[m * 256 + lane + 64] +
                  e[m * 256 + lane + 128] + e[m * 256 + lane + 192];
        #pragma unroll
        for (int off = 32; off >= 1; off >>= 1) v += __shfl_xor(v, off);
        if (lane == 0) ssum[m] = __frcp_rn(v);
    }
    __syncthreads();

    // pooled[s] = 0.25 * sum_h (sum_l attn^4)^(1/4)
    if (t < 256) {
        float r = 0.f;
        #pragma unroll
        for (int h = 0; h < HH; ++h) {
            float p4 = 0.f;
            #pragma unroll
            for (int l = 0; l < LL; ++l) {
                int m = h * LL + l;
                float a = e[m * 256 + t] * ssum[m];
                float a2 = a * a;
                p4 += a2 * a2;
            }
            r += sqrtf(sqrtf(p4));
        }
        pooled[t] = 0.25f * r;
    }
    __syncthreads();

    // phase C: out[b,d] = sum_s pooled[s] * emb[seq[b,s], d]  (fp32, coalesced)
    int d = t & 255, sq = t >> 8;
    float o = 0.f;
    for (int i = 0; i < 50; ++i) {
        int s2 = sq * 50 + i;
        int rw = __builtin_amdgcn_readfirstlane(seq[b * SS + s2]);
        o = fmaf(pooled[s2], emb[(size_t)rw * DD + d], o);
    }
    par[sq * 256 + d] = o;
    __syncthreads();
    if (t < 256) out[(size_t)b * DD + t] =
        par[t] + par[256 + t] + par[512 + t] + par[768 + t];
}

extern "C" void kernel_launch(void* const* d_in, const int* in_sizes, int n_in,
                              void* d_out, int out_size, void* d_ws, size_t ws_size,
                              hipStream_t stream) {
    const int* seq = (const int*)d_in[0];
    const int* slen = (const int*)d_in[1];
    const float* emb = (const float*)d_in[2];
    const float* lin = (const float*)d_in[3];
    const float* wq = (const float*)d_in[4];
    const float* wk = (const float*)d_in[5];
    float* out = (float*)d_out;
    float* ws = (float*)d_ws;

    float* U    = ws;                // H * D*D   = 262144 floats
    float* qpre = ws + 262144;       // [l][b][d] = 327680
    float* ql   = ws + 589824;       // [l][b][d] = 327680
    float* Qt   = ws + 917504;       // [m][b][d] = 1310720
    // total 2,228,224 floats = 8.9 MB workspace

    k_qpre<<<dim3(BB), dim3(256), 0, stream>>>(seq, slen, emb, qpre);
    k_wu<<<dim3(144), dim3(256), 0, stream>>>(wq, wk, qpre, lin, U, ql);
    k_Qt<<<dim3(320), dim3(256), 0, stream>>>(ql, U, Qt);
    k_attn_out<<<dim3(BB), dim3(1024), 0, stream>>>(seq, emb, Qt, out);
}